// Round 10
// baseline (790.824 us; speedup 1.0000x reference)
//
#include <hip/hip_runtime.h>

#define HID 2048
#define INTER 1408
#define NEXP 14
#define SINTER 2816
#define TTOK 2048
#define BM 256
#define BK 64

#define GLU_SH 88    // 11 nt x 8? -> 22? : SINTER/128=22 nt... (see decode: 22nt x 4ms = 88)
#define GLU_RT 154   // 14 e x 11 nt
#define DWN_SH 64    // 16 nt x 4 ms
#define DWN_RT 224   // 14 e x 16 nt

typedef short bf16x8 __attribute__((ext_vector_type(8)));
typedef float f32x4 __attribute__((ext_vector_type(4)));
typedef unsigned short u16x8 __attribute__((ext_vector_type(8)));

__device__ __forceinline__ unsigned short f2bf(float f) {
    __bf16 b = (__bf16)f;
    return __builtin_bit_cast(unsigned short, b);
}
__device__ __forceinline__ float bf2f(unsigned short u) {
    unsigned v = (unsigned)u << 16;
    return __builtin_bit_cast(float, v);
}
// swizzles: 128B-stride rows (K-tiles), 256B-stride rows (epilogue h tile)
__device__ __forceinline__ unsigned swz(unsigned b)    { return b ^ (((b >> 7) & 7u) << 4); }
__device__ __forceinline__ unsigned swz256(unsigned b) { return b ^ (((b >> 8) & 7u) << 4); }

__device__ __forceinline__ void gload16(const void* g, void* l) {
    __builtin_amdgcn_global_load_lds((__attribute__((address_space(1))) void*)g,
                                     (__attribute__((address_space(3))) void*)l, 16, 0, 0);
}
__device__ __forceinline__ void bsync() {
    __builtin_amdgcn_sched_barrier(0);
    __builtin_amdgcn_s_barrier();
    __builtin_amdgcn_sched_barrier(0);
}
#define WAIT_VM_(n) asm volatile("s_waitcnt vmcnt(" #n ")" ::: "memory")
#define WAIT_VM(n) WAIT_VM_(n)
#define FENCE __builtin_amdgcn_sched_barrier(0)
#define MFMA16(a, b, c) __builtin_amdgcn_mfma_f32_16x16x32_bf16(a, b, c, 0, 0, 0)

__global__ void k_zero(int* cnt) {
    if ((int)threadIdx.x < NEXP) cnt[threadIdx.x] = 0;
}

// fp32 -> bf16 stream conversion (grid-stride, 8 elems/thread/iter)
__global__ __launch_bounds__(256) void k_w2b(const float* __restrict__ src,
                                             unsigned short* __restrict__ dst, int n8) {
    int stride = gridDim.x * 256;
    for (int i = blockIdx.x * 256 + threadIdx.x; i < n8; i += stride) {
        size_t o = (size_t)i * 8;
        float4 a = *(const float4*)(src + o);
        float4 b = *(const float4*)(src + o + 4);
        u16x8 v;
        v[0] = f2bf(a.x); v[1] = f2bf(a.y); v[2] = f2bf(a.z); v[3] = f2bf(a.w);
        v[4] = f2bf(b.x); v[5] = f2bf(b.y); v[6] = f2bf(b.z); v[7] = f2bf(b.w);
        *(u16x8*)(dst + o) = v;
    }
}

// Router (fused x->bf16). One wave per token.
__global__ __launch_bounds__(256) void k_router(
    const float* __restrict__ x,
    const float* __restrict__ gate_w, const float* __restrict__ cls_w,
    const float* __restrict__ escale, const float* __restrict__ ebias,
    int* __restrict__ cnt, int* __restrict__ etok, float* __restrict__ ew,
    unsigned short* __restrict__ xb) {
    const int lane = threadIdx.x & 63;
    const int tok = blockIdx.x * 4 + (threadIdx.x >> 6);
    const float* xr = x + (size_t)tok * HID;
    float xv[32];
#pragma unroll
    for (int i = 0; i < 32; i++) xv[i] = xr[lane + 64 * i];
    unsigned short* xbr = xb + (size_t)tok * HID;
#pragma unroll
    for (int i = 0; i < 32; i++) xbr[lane + 64 * i] = f2bf(xv[i]);

    float sc[NEXP];
    float mx = 0.f;
#pragma unroll
    for (int e = 0; e < NEXP; e++) {
        const float* cw = cls_w + (size_t)e * HID;
        const float* gw = gate_w + (size_t)e * HID;
        float pc = 0.f, pg = 0.f;
#pragma unroll
        for (int i = 0; i < 32; i++) {
            float v = xv[i];
            pc = fmaf(v, cw[lane + 64 * i], pc);
            pg = fmaf(v, gw[lane + 64 * i], pg);
        }
#pragma unroll
        for (int o = 32; o >= 1; o >>= 1) {
            pc += __shfl_xor(pc, o);
            pg += __shfl_xor(pg, o);
        }
        float lg = pc * (pg / (1.f + __expf(-pg)));
        sc[e] = fabsf(lg);
        mx = fmaxf(mx, sc[e]);
    }
    float s = 0.f;
#pragma unroll
    for (int e = 0; e < NEXP; e++) { sc[e] = __expf(sc[e] - mx); s += sc[e]; }
    float inv = 1.f / s;
    int i1 = -1, i2 = -1;
    float b1 = -1e30f, b2 = -1e30f, v1 = 0.f, v2 = 0.f;
#pragma unroll
    for (int e = 0; e < NEXP; e++) {
        float sv = sc[e] * inv;
        float b = sv + ebias[e];
        if (b > b1) { b2 = b1; i2 = i1; v2 = v1; b1 = b; i1 = e; v1 = sv; }
        else if (b > b2) { b2 = b; i2 = e; v2 = sv; }
    }
    if (lane == 0) {
        float w1 = 1.f + v1 * escale[i1];
        float w2 = 1.f + v2 * escale[i2];
        int p1 = atomicAdd(&cnt[i1], 1);
        etok[i1 * TTOK + p1] = tok * 2;     ew[i1 * TTOK + p1] = w1;
        int p2 = atomicAdd(&cnt[i2], 1);
        etok[i2 * TTOK + p2] = tok * 2 + 1; ew[i2 * TTOK + p2] = w2;
    }
}

__global__ void k_offsets(const int* __restrict__ cnt, int* __restrict__ offs) {
    if (threadIdx.x == 0) {
        int a = 0;
        for (int e = 0; e < NEXP; e++) { offs[e] = a; a += cnt[e]; }
    }
}

// Gate+up GEMM, pure-DMA. BM=256, BN=128(G)+128(U), BK=64, 1024 thr / 16 waves (8m x 2n).
// A (xb) and B (bf16 weights) both via global_load_lds, double-buffered, counted vmcnt(4).
__global__ __launch_bounds__(1024, 4) void k_glu10(
    const unsigned short* __restrict__ xb,
    const unsigned short* __restrict__ wgb, const unsigned short* __restrict__ wub,
    const unsigned short* __restrict__ sgb, const unsigned short* __restrict__ sub,
    unsigned short* __restrict__ abuf, unsigned short* __restrict__ hbuf,
    const int* __restrict__ cnt, const int* __restrict__ offs,
    const int* __restrict__ etok) {
    __shared__ alignas(16) unsigned short sA[2][BM * BK];    // 2 x 32 KB
    __shared__ alignas(16) unsigned short sBg[2][128 * BK];  // 2 x 16 KB
    __shared__ alignas(16) unsigned short sBu[2][128 * BK];  // 2 x 16 KB

    const int bx = blockIdx.x, t = threadIdx.x;
    const int lane = t & 63, w = t >> 6;           // 16 waves
    const int wm = w >> 1, wn = w & 1;
    const int fr = lane & 15, fo = lane >> 4;

    const bool routed = bx >= GLU_SH;
    int n0, m_start, m_stop, obase, Ntot;
    const unsigned short *Bg, *Bu;
    unsigned short* outp;
    const int* etk = nullptr;
    if (routed) {
        int rx = bx - GLU_SH;
        int e = rx / 11; n0 = (rx % 11) * 128;
        int M = cnt[e];
        if (M <= 0) return;
        m_start = 0; m_stop = M; obase = offs[e]; Ntot = INTER;
        Bg = wgb + ((size_t)e * INTER + n0) * HID;
        Bu = wub + ((size_t)e * INTER + n0) * HID;
        outp = abuf; etk = etok + e * TTOK;
    } else {
        n0 = (bx >> 2) * 128;                      // 22 n-tiles x 4 m-slices
        m_start = (bx & 3) * 512; m_stop = m_start + 512;
        obase = 0; Ntot = SINTER;
        Bg = sgb + (size_t)n0 * HID;
        Bu = sub + (size_t)n0 * HID;
        outp = hbuf;
    }

    const int browo = lane >> 3;                   // 0..7
    const int achunk = (lane & 7) ^ browo;         // pre-swizzled source chunk
    // B sources: wave w stages Bg rows w*8..+7 and Bu rows w*8..+7 (1 issue each)
    const unsigned short* srcBg = Bg + (size_t)(w * 8 + browo) * HID + achunk * 8;
    const unsigned short* srcBu = Bu + (size_t)(w * 8 + browo) * HID + achunk * 8;

    unsigned aoff[2][2], boff[4][2];
#pragma unroll
    for (int mi = 0; mi < 2; mi++)
#pragma unroll
        for (int ks = 0; ks < 2; ks++)
            aoff[mi][ks] = swz((unsigned)((wm * 32 + mi * 16 + fr) * 128 + ks * 64 + fo * 16));
#pragma unroll
    for (int nj = 0; nj < 4; nj++)
#pragma unroll
        for (int ks = 0; ks < 2; ks++)
            boff[nj][ks] = swz((unsigned)((wn * 64 + nj * 16 + fr) * 128 + ks * 64 + fo * 16));

    for (int m0 = m_start; m0 < m_stop; m0 += BM) {
        const int rv = min(m_stop - m0, BM);
        const unsigned short* srcA[2];
#pragma unroll
        for (int j = 0; j < 2; j++) {              // A: wave w stages rows w*16 + j*8 ..+7
            int r = w * 16 + j * 8 + browo;
            int rr = r < rv ? r : rv - 1;
            int tok = routed ? (etk[m0 + rr] >> 1) : (m0 + rr);
            srcA[j] = xb + (size_t)tok * HID + achunk * 8;
        }

        f32x4 ag[2][4], au[2][4];
#pragma unroll
        for (int mi = 0; mi < 2; mi++)
#pragma unroll
            for (int nj = 0; nj < 4; nj++) { ag[mi][nj] = {0.f,0.f,0.f,0.f}; au[mi][nj] = {0.f,0.f,0.f,0.f}; }

        // prologue: set(0) -> buf0  (4 issues per wave)
#pragma unroll
        for (int j = 0; j < 2; j++)
            gload16(srcA[j], (char*)sA[0] + w * 2048 + j * 1024);
        gload16(srcBg, (char*)sBg[0] + w * 1024);
        gload16(srcBu, (char*)sBu[0] + w * 1024);

        for (int kk = 0; kk < HID / BK; ++kk) {
            const int cur = kk & 1;
            bsync();                               // prior reads of buf[cur^1] done
            if (kk + 1 < HID / BK) {
                const int k1 = (kk + 1) * BK;
#pragma unroll
                for (int j = 0; j < 2; j++)
                    gload16(srcA[j] + k1, (char*)sA[cur ^ 1] + w * 2048 + j * 1024);
                gload16(srcBg + k1, (char*)sBg[cur ^ 1] + w * 1024);
                gload16(srcBu + k1, (char*)sBu[cur ^ 1] + w * 1024);
                FENCE; WAIT_VM(4); FENCE;          // drain set(kk), keep set(kk+1) in flight
            } else {
                FENCE; WAIT_VM(0); FENCE;
            }
            bsync();                               // tile kk visible to all waves
#pragma unroll
            for (int ks = 0; ks < 2; ++ks) {
                bf16x8 af[2], gf[4], uf[4];
#pragma unroll
                for (int mi = 0; mi < 2; mi++) af[mi] = *(const bf16x8*)((const char*)sA[cur] + aoff[mi][ks]);
#pragma unroll
                for (int nj = 0; nj < 4; nj++) {
                    gf[nj] = *(const bf16x8*)((const char*)sBg[cur] + boff[nj][ks]);
                    uf[nj] = *(const bf16x8*)((const char*)sBu[cur] + boff[nj][ks]);
                }
#pragma unroll
                for (int mi = 0; mi < 2; mi++)
#pragma unroll
                    for (int nj = 0; nj < 4; nj++) {
                        ag[mi][nj] = MFMA16(af[mi], gf[nj], ag[mi][nj]);
                        au[mi][nj] = MFMA16(af[mi], uf[nj], au[mi][nj]);
                    }
            }
        }

        // epilogue: h = silu(g)*u -> stage bf16 [256][128] over both A bufs -> sweep
        bsync();                                   // all MFMA reads done before overwrite
        char* sH = (char*)sA;
#pragma unroll
        for (int mi = 0; mi < 2; mi++)
#pragma unroll
            for (int jj = 0; jj < 4; jj++) {
                int r = wm * 32 + mi * 16 + fo * 4 + jj;
#pragma unroll
                for (int nj = 0; nj < 4; nj++) {
                    int c = wn * 64 + nj * 16 + fr;
                    float g = ag[mi][nj][jj];
                    float u = au[mi][nj][jj];
                    float h = (g / (1.f + __expf(-g))) * u;
                    *(unsigned short*)(sH + swz256((unsigned)(r * 256 + c * 2))) = f2bf(h);
                }
            }
        asm volatile("s_waitcnt lgkmcnt(0)" ::: "memory");
        bsync();
#pragma unroll
        for (int q = 0; q < 4; q++) {
            int idx = q * 1024 + t;
            int r = idx >> 4, c16 = idx & 15;
            if (r < rv) {
                uint4 v = *(const uint4*)(sH + swz256((unsigned)(r * 256 + c16 * 16)));
                *(uint4*)(outp + (size_t)(obase + m0 + r) * Ntot + n0 + c16 * 8) = v;
            }
        }
        bsync();                                   // sweep reads done before next prologue
    }
}

// Down GEMM, pure-DMA. BM=256, BN=128, BK=64, 1024 thr / 16 waves (8m x 2n).
__global__ __launch_bounds__(1024, 4) void k_down10(
    const unsigned short* __restrict__ abuf, const unsigned short* __restrict__ hbuf,
    const unsigned short* __restrict__ wdb, const unsigned short* __restrict__ sdb,
    unsigned short* __restrict__ slots,
    const int* __restrict__ cnt, const int* __restrict__ offs,
    const int* __restrict__ etok, const float* __restrict__ ew) {
    __shared__ alignas(16) unsigned short sA[2][BM * BK];   // 2 x 32 KB
    __shared__ alignas(16) unsigned short sB[2][128 * BK];  // 2 x 16 KB

    const int bx = blockIdx.x, t = threadIdx.x;
    const int lane = t & 63, w = t >> 6;
    const int wm = w >> 1, wn = w & 1;
    const int fr = lane & 15, fo = lane >> 4;

    const bool routed = bx >= DWN_SH;
    int n0, m_start, m_stop, K, KT;
    const unsigned short* W;
    const unsigned short* Abuf;
    size_t arow0 = 0;
    const int* etk = nullptr; const float* ewe = nullptr;
    if (routed) {
        int rx = bx - DWN_SH;
        int e = rx / 16; n0 = (rx % 16) * 128;
        int M = cnt[e];
        if (M <= 0) return;
        m_start = 0; m_stop = M;
        K = INTER; KT = INTER / BK;
        W = wdb + (size_t)e * HID * INTER + (size_t)n0 * INTER;
        Abuf = abuf; arow0 = offs[e];
        etk = etok + e * TTOK; ewe = ew + e * TTOK;
    } else {
        n0 = (bx >> 2) * 128;                      // 16 nt x 4 ms
        m_start = (bx & 3) * 512; m_stop = m_start + 512;
        K = SINTER; KT = SINTER / BK;
        W = sdb + (size_t)n0 * SINTER;
        Abuf = hbuf;
    }

    const int browo = lane >> 3;
    const int achunk = (lane & 7) ^ browo;
    const unsigned short* srcB = W + (size_t)(w * 8 + browo) * K + achunk * 8;

    unsigned aoff[2][2], boff[4][2];
#pragma unroll
    for (int mi = 0; mi < 2; mi++)
#pragma unroll
        for (int ks = 0; ks < 2; ks++)
            aoff[mi][ks] = swz((unsigned)((wm * 32 + mi * 16 + fr) * 128 + ks * 64 + fo * 16));
#pragma unroll
    for (int nj = 0; nj < 4; nj++)
#pragma unroll
        for (int ks = 0; ks < 2; ks++)
            boff[nj][ks] = swz((unsigned)((wn * 64 + nj * 16 + fr) * 128 + ks * 64 + fo * 16));

    for (int m0 = m_start; m0 < m_stop; m0 += BM) {
        const int rv = min(m_stop - m0, BM);
        const unsigned short* srcA[2];
#pragma unroll
        for (int j = 0; j < 2; j++) {
            int r = w * 16 + j * 8 + browo;
            int rr = r < rv ? r : rv - 1;
            srcA[j] = Abuf + (arow0 + m0 + rr) * (size_t)K + achunk * 8;
        }

        f32x4 ac[2][4];
#pragma unroll
        for (int mi = 0; mi < 2; mi++)
#pragma unroll
            for (int nj = 0; nj < 4; nj++) ac[mi][nj] = {0.f, 0.f, 0.f, 0.f};

#pragma unroll
        for (int j = 0; j < 2; j++)
            gload16(srcA[j], (char*)sA[0] + w * 2048 + j * 1024);
        gload16(srcB, (char*)sB[0] + w * 1024);

        for (int kk = 0; kk < KT; ++kk) {
            const int cur = kk & 1;
            bsync();
            if (kk + 1 < KT) {
                const int k1 = (kk + 1) * BK;
#pragma unroll
                for (int j = 0; j < 2; j++)
                    gload16(srcA[j] + k1, (char*)sA[cur ^ 1] + w * 2048 + j * 1024);
                gload16(srcB + k1, (char*)sB[cur ^ 1] + w * 1024);
                FENCE; WAIT_VM(3); FENCE;
            } else {
                FENCE; WAIT_VM(0); FENCE;
            }
            bsync();
#pragma unroll
            for (int ks = 0; ks < 2; ++ks) {
                bf16x8 af[2], bf[4];
#pragma unroll
                for (int mi = 0; mi < 2; mi++) af[mi] = *(const bf16x8*)((const char*)sA[cur] + aoff[mi][ks]);
#pragma unroll
                for (int nj = 0; nj < 4; nj++) bf[nj] = *(const bf16x8*)((const char*)sB[cur] + boff[nj][ks]);
#pragma unroll
                for (int mi = 0; mi < 2; mi++)
#pragma unroll
                    for (int nj = 0; nj < 4; nj++)
                        ac[mi][nj] = MFMA16(af[mi], bf[nj], ac[mi][nj]);
            }
        }

        // epilogue: scale, stage bf16 [256][128] over both A bufs, sweep to slot slices
        bsync();
        char* sH = (char*)sA;
#pragma unroll
        for (int mi = 0; mi < 2; mi++)
#pragma unroll
            for (int jj = 0; jj < 4; jj++) {
                int r = wm * 32 + mi * 16 + fo * 4 + jj;
                float wt = 1.f;
                if (routed) wt = (r < rv) ? ewe[m0 + r] : 0.f;
#pragma unroll
                for (int nj = 0; nj < 4; nj++) {
                    int c = wn * 64 + nj * 16 + fr;
                    *(unsigned short*)(sH + swz256((unsigned)(r * 256 + c * 2))) =
                        f2bf(ac[mi][nj][jj] * wt);
                }
            }
        asm volatile("s_waitcnt lgkmcnt(0)" ::: "memory");
        bsync();
#pragma unroll
        for (int q = 0; q < 4; q++) {
            int idx = q * 1024 + t;
            int r = idx >> 4, c16 = idx & 15;
            if (r < rv) {
                uint4 v = *(const uint4*)(sH + swz256((unsigned)(r * 256 + c16 * 16)));
                int tok, slice;
                if (routed) { int entry = etk[m0 + r]; tok = entry >> 1; slice = entry & 1; }
                else        { tok = m0 + r; slice = 2; }
                *(uint4*)(slots + ((size_t)slice * TTOK + tok) * HID + n0 + c16 * 8) = v;
            }
        }
        bsync();
    }
}

__global__ __launch_bounds__(256) void k_final(float* __restrict__ out,
                                               const unsigned short* __restrict__ slots) {
    size_t i = ((size_t)blockIdx.x * 256 + threadIdx.x) * 8;
    u16x8 s0 = *(const u16x8*)(slots + i);
    u16x8 s1 = *(const u16x8*)(slots + (size_t)TTOK * HID + i);
    u16x8 s2 = *(const u16x8*)(slots + (size_t)2 * TTOK * HID + i);
    float4 o0, o1;
    o0.x = bf2f(s0[0]) + bf2f(s1[0]) + bf2f(s2[0]);
    o0.y = bf2f(s0[1]) + bf2f(s1[1]) + bf2f(s2[1]);
    o0.z = bf2f(s0[2]) + bf2f(s1[2]) + bf2f(s2[2]);
    o0.w = bf2f(s0[3]) + bf2f(s1[3]) + bf2f(s2[3]);
    o1.x = bf2f(s0[4]) + bf2f(s1[4]) + bf2f(s2[4]);
    o1.y = bf2f(s0[5]) + bf2f(s1[5]) + bf2f(s2[5]);
    o1.z = bf2f(s0[6]) + bf2f(s1[6]) + bf2f(s2[6]);
    o1.w = bf2f(s0[7]) + bf2f(s1[7]) + bf2f(s2[7]);
    *(float4*)(out + i) = o0;
    *(float4*)(out + i + 4) = o1;
}

extern "C" void kernel_launch(void* const* d_in, const int* in_sizes, int n_in,
                              void* d_out, int out_size, void* d_ws, size_t ws_size,
                              hipStream_t stream) {
    const float* x = (const float*)d_in[0];
    const float* gate_w = (const float*)d_in[1];
    const float* cls_w = (const float*)d_in[2];
    const float* escale = (const float*)d_in[3];
    const float* ebias = (const float*)d_in[4];
    const float* wg = (const float*)d_in[5];
    const float* wu = (const float*)d_in[6];
    const float* wd = (const float*)d_in[7];
    const float* sg = (const float*)d_in[8];
    const float* su = (const float*)d_in[9];
    const float* sd = (const float*)d_in[10];
    float* out = (float*)d_out;

    char* ws = (char*)d_ws;
    size_t o = 0;
    auto alloc = [&](size_t bytes) {
        char* p = ws + o;
        o += (bytes + 255) & ~(size_t)255;
        return p;
    };
    const size_t WN = (size_t)NEXP * INTER * HID;     // 40,370,176 elems
    const size_t SN = (size_t)SINTER * HID;           // 5,767,168 elems
    unsigned short* xb    = (unsigned short*)alloc((size_t)TTOK * HID * 2);
    unsigned short* hbuf  = (unsigned short*)alloc((size_t)TTOK * SINTER * 2);
    unsigned short* abuf  = (unsigned short*)alloc((size_t)2 * TTOK * INTER * 2);
    unsigned short* slots = (unsigned short*)alloc((size_t)3 * TTOK * HID * 2);
    unsigned short* wgb   = (unsigned short*)alloc(WN * 2);
    unsigned short* wub   = (unsigned short*)alloc(WN * 2);
    unsigned short* wdb   = (unsigned short*)alloc(WN * 2);
    unsigned short* sgb   = (unsigned short*)alloc(SN * 2);
    unsigned short* subb  = (unsigned short*)alloc(SN * 2);
    unsigned short* sdb   = (unsigned short*)alloc(SN * 2);
    int* cnt              = (int*)alloc(256);
    int* offs             = (int*)alloc(256);
    int* etok             = (int*)alloc((size_t)NEXP * TTOK * 4);
    float* ew             = (float*)alloc((size_t)NEXP * TTOK * 4);

    k_zero<<<1, 64, 0, stream>>>(cnt);
    k_w2b<<<4096, 256, 0, stream>>>(wg, wgb, (int)(WN / 8));
    k_w2b<<<4096, 256, 0, stream>>>(wu, wub, (int)(WN / 8));
    k_w2b<<<4096, 256, 0, stream>>>(wd, wdb, (int)(WN / 8));
    k_w2b<<<1024, 256, 0, stream>>>(sg, sgb, (int)(SN / 8));
    k_w2b<<<1024, 256, 0, stream>>>(su, subb, (int)(SN / 8));
    k_w2b<<<1024, 256, 0, stream>>>(sd, sdb, (int)(SN / 8));
    k_router<<<512, 256, 0, stream>>>(x, gate_w, cls_w, escale, ebias, cnt, etok, ew, xb);
    k_offsets<<<1, 64, 0, stream>>>(cnt, offs);
    k_glu10<<<GLU_SH + GLU_RT, 1024, 0, stream>>>(
        xb, wgb, wub, sgb, subb, abuf, hbuf, cnt, offs, etok);
    k_down10<<<DWN_SH + DWN_RT, 1024, 0, stream>>>(
        abuf, hbuf, wdb, sdb, slots, cnt, offs, etok, ew);
    k_final<<<2048, 256, 0, stream>>>(out, slots);
}

// Round 11
// 625.133 us; speedup vs baseline: 1.2651x; 1.2651x over previous
//
#include <hip/hip_runtime.h>

#define HID 2048
#define INTER 1408
#define NEXP 14
#define SINTER 2816
#define TTOK 2048
#define BM 256
#define BK 64

#define GLU_SH 88    // 22 nt x 4 m-slices (shared)
#define GLU_RT 154   // 14 e x 11 nt
#define DWN_SH 64    // 16 nt x 4 ms
#define DWN_RT 224   // 14 e x 16 nt

typedef short bf16x8 __attribute__((ext_vector_type(8)));
typedef float f32x4 __attribute__((ext_vector_type(4)));
typedef unsigned short u16x8 __attribute__((ext_vector_type(8)));

__device__ __forceinline__ unsigned short f2bf(float f) {
    __bf16 b = (__bf16)f;
    return __builtin_bit_cast(unsigned short, b);
}
__device__ __forceinline__ float bf2f(unsigned short u) {
    unsigned v = (unsigned)u << 16;
    return __builtin_bit_cast(float, v);
}
// swizzles: 128B-stride rows (K-tiles), 256B-stride rows (epilogue h tile)
__device__ __forceinline__ unsigned swz(unsigned b)    { return b ^ (((b >> 7) & 7u) << 4); }
__device__ __forceinline__ unsigned swz256(unsigned b) { return b ^ (((b >> 8) & 7u) << 4); }

__device__ __forceinline__ void gload16(const void* g, void* l) {
    __builtin_amdgcn_global_load_lds((__attribute__((address_space(1))) void*)g,
                                     (__attribute__((address_space(3))) void*)l, 16, 0, 0);
}
__device__ __forceinline__ void bsync() {
    __builtin_amdgcn_sched_barrier(0);
    __builtin_amdgcn_s_barrier();
    __builtin_amdgcn_sched_barrier(0);
}
#define WAIT_VM_(n) asm volatile("s_waitcnt vmcnt(" #n ")" ::: "memory")
#define WAIT_VM(n) WAIT_VM_(n)
#define FENCE __builtin_amdgcn_sched_barrier(0)
#define MFMA16(a, b, c) __builtin_amdgcn_mfma_f32_16x16x32_bf16(a, b, c, 0, 0, 0)

__global__ void k_zero(int* cnt) {
    if ((int)threadIdx.x < NEXP) cnt[threadIdx.x] = 0;
}

// fp32 -> bf16 stream conversion (grid-stride, 8 elems/thread/iter)
__global__ __launch_bounds__(256) void k_w2b(const float* __restrict__ src,
                                             unsigned short* __restrict__ dst, int n8) {
    int stride = gridDim.x * 256;
    for (int i = blockIdx.x * 256 + threadIdx.x; i < n8; i += stride) {
        size_t o = (size_t)i * 8;
        float4 a = *(const float4*)(src + o);
        float4 b = *(const float4*)(src + o + 4);
        u16x8 v;
        v[0] = f2bf(a.x); v[1] = f2bf(a.y); v[2] = f2bf(a.z); v[3] = f2bf(a.w);
        v[4] = f2bf(b.x); v[5] = f2bf(b.y); v[6] = f2bf(b.z); v[7] = f2bf(b.w);
        *(u16x8*)(dst + o) = v;
    }
}

// Router, vectorized: one wave per token; lane covers elems lane*4 + i*256.
// fp32 math (expert selection must match reference); batched float4 loads for MLP.
__global__ __launch_bounds__(256, 4) void k_router(
    const float* __restrict__ x,
    const float* __restrict__ gate_w, const float* __restrict__ cls_w,
    const float* __restrict__ escale, const float* __restrict__ ebias,
    int* __restrict__ cnt, int* __restrict__ etok, float* __restrict__ ew) {
    const int lane = threadIdx.x & 63;
    const int tok = blockIdx.x * 4 + (threadIdx.x >> 6);
    const float* xr = x + (size_t)tok * HID + lane * 4;
    float4 xv[8];
#pragma unroll
    for (int i = 0; i < 8; i++) xv[i] = *(const float4*)(xr + i * 256);

    float sc[NEXP];
    float mx = 0.f;
#pragma unroll
    for (int e = 0; e < NEXP; e++) {
        const float* cw = cls_w + (size_t)e * HID + lane * 4;
        const float* gw = gate_w + (size_t)e * HID + lane * 4;
        float pc = 0.f, pg = 0.f;
        {   // batch 1: classifier row (8 independent float4 loads, then fmaf)
            float4 cv[8];
#pragma unroll
            for (int i = 0; i < 8; i++) cv[i] = *(const float4*)(cw + i * 256);
#pragma unroll
            for (int i = 0; i < 8; i++) {
                pc = fmaf(xv[i].x, cv[i].x, pc);
                pc = fmaf(xv[i].y, cv[i].y, pc);
                pc = fmaf(xv[i].z, cv[i].z, pc);
                pc = fmaf(xv[i].w, cv[i].w, pc);
            }
        }
        {   // batch 2: gate row
            float4 gv[8];
#pragma unroll
            for (int i = 0; i < 8; i++) gv[i] = *(const float4*)(gw + i * 256);
#pragma unroll
            for (int i = 0; i < 8; i++) {
                pg = fmaf(xv[i].x, gv[i].x, pg);
                pg = fmaf(xv[i].y, gv[i].y, pg);
                pg = fmaf(xv[i].z, gv[i].z, pg);
                pg = fmaf(xv[i].w, gv[i].w, pg);
            }
        }
#pragma unroll
        for (int o = 32; o >= 1; o >>= 1) {
            pc += __shfl_xor(pc, o);
            pg += __shfl_xor(pg, o);
        }
        float lg = pc * (pg / (1.f + __expf(-pg)));   // cls * silu(gate)
        sc[e] = fabsf(lg);
        mx = fmaxf(mx, sc[e]);
    }
    float s = 0.f;
#pragma unroll
    for (int e = 0; e < NEXP; e++) { sc[e] = __expf(sc[e] - mx); s += sc[e]; }
    float inv = 1.f / s;
    int i1 = -1, i2 = -1;
    float b1 = -1e30f, b2 = -1e30f, v1 = 0.f, v2 = 0.f;
#pragma unroll
    for (int e = 0; e < NEXP; e++) {
        float sv = sc[e] * inv;
        float b = sv + ebias[e];
        if (b > b1) { b2 = b1; i2 = i1; v2 = v1; b1 = b; i1 = e; v1 = sv; }
        else if (b > b2) { b2 = b; i2 = e; v2 = sv; }
    }
    if (lane == 0) {
        float w1 = 1.f + v1 * escale[i1];
        float w2 = 1.f + v2 * escale[i2];
        int p1 = atomicAdd(&cnt[i1], 1);
        etok[i1 * TTOK + p1] = tok * 2;     ew[i1 * TTOK + p1] = w1;
        int p2 = atomicAdd(&cnt[i2], 1);
        etok[i2 * TTOK + p2] = tok * 2 + 1; ew[i2 * TTOK + p2] = w2;
    }
}

__global__ void k_offsets(const int* __restrict__ cnt, int* __restrict__ offs) {
    if (threadIdx.x == 0) {
        int a = 0;
        for (int e = 0; e < NEXP; e++) { offs[e] = a; a += cnt[e]; }
    }
}

// Gate+up GEMM, pure-DMA. BM=256, BN=128(G)+128(U), BK=64, 1024 thr / 16 waves (8m x 2n).
__global__ __launch_bounds__(1024, 4) void k_glu10(
    const unsigned short* __restrict__ xb,
    const unsigned short* __restrict__ wgb, const unsigned short* __restrict__ wub,
    const unsigned short* __restrict__ sgb, const unsigned short* __restrict__ sub,
    unsigned short* __restrict__ abuf, unsigned short* __restrict__ hbuf,
    const int* __restrict__ cnt, const int* __restrict__ offs,
    const int* __restrict__ etok) {
    __shared__ alignas(16) unsigned short sA[2][BM * BK];    // 2 x 32 KB
    __shared__ alignas(16) unsigned short sBg[2][128 * BK];  // 2 x 16 KB
    __shared__ alignas(16) unsigned short sBu[2][128 * BK];  // 2 x 16 KB

    const int bx = blockIdx.x, t = threadIdx.x;
    const int lane = t & 63, w = t >> 6;
    const int wm = w >> 1, wn = w & 1;
    const int fr = lane & 15, fo = lane >> 4;

    const bool routed = bx >= GLU_SH;
    int n0, m_start, m_stop, obase, Ntot;
    const unsigned short *Bg, *Bu;
    unsigned short* outp;
    const int* etk = nullptr;
    if (routed) {
        int rx = bx - GLU_SH;
        int e = rx / 11; n0 = (rx % 11) * 128;
        int M = cnt[e];
        if (M <= 0) return;
        m_start = 0; m_stop = M; obase = offs[e]; Ntot = INTER;
        Bg = wgb + ((size_t)e * INTER + n0) * HID;
        Bu = wub + ((size_t)e * INTER + n0) * HID;
        outp = abuf; etk = etok + e * TTOK;
    } else {
        n0 = (bx >> 2) * 128;
        m_start = (bx & 3) * 512; m_stop = m_start + 512;
        obase = 0; Ntot = SINTER;
        Bg = sgb + (size_t)n0 * HID;
        Bu = sub + (size_t)n0 * HID;
        outp = hbuf;
    }

    const int browo = lane >> 3;
    const int achunk = (lane & 7) ^ browo;
    const unsigned short* srcBg = Bg + (size_t)(w * 8 + browo) * HID + achunk * 8;
    const unsigned short* srcBu = Bu + (size_t)(w * 8 + browo) * HID + achunk * 8;

    unsigned aoff[2][2], boff[4][2];
#pragma unroll
    for (int mi = 0; mi < 2; mi++)
#pragma unroll
        for (int ks = 0; ks < 2; ks++)
            aoff[mi][ks] = swz((unsigned)((wm * 32 + mi * 16 + fr) * 128 + ks * 64 + fo * 16));
#pragma unroll
    for (int nj = 0; nj < 4; nj++)
#pragma unroll
        for (int ks = 0; ks < 2; ks++)
            boff[nj][ks] = swz((unsigned)((wn * 64 + nj * 16 + fr) * 128 + ks * 64 + fo * 16));

    for (int m0 = m_start; m0 < m_stop; m0 += BM) {
        const int rv = min(m_stop - m0, BM);
        const unsigned short* srcA[2];
#pragma unroll
        for (int j = 0; j < 2; j++) {
            int r = w * 16 + j * 8 + browo;
            int rr = r < rv ? r : rv - 1;
            int tok = routed ? (etk[m0 + rr] >> 1) : (m0 + rr);
            srcA[j] = xb + (size_t)tok * HID + achunk * 8;
        }

        f32x4 ag[2][4], au[2][4];
#pragma unroll
        for (int mi = 0; mi < 2; mi++)
#pragma unroll
            for (int nj = 0; nj < 4; nj++) { ag[mi][nj] = {0.f,0.f,0.f,0.f}; au[mi][nj] = {0.f,0.f,0.f,0.f}; }

#pragma unroll
        for (int j = 0; j < 2; j++)
            gload16(srcA[j], (char*)sA[0] + w * 2048 + j * 1024);
        gload16(srcBg, (char*)sBg[0] + w * 1024);
        gload16(srcBu, (char*)sBu[0] + w * 1024);

        for (int kk = 0; kk < HID / BK; ++kk) {
            const int cur = kk & 1;
            bsync();
            if (kk + 1 < HID / BK) {
                const int k1 = (kk + 1) * BK;
#pragma unroll
                for (int j = 0; j < 2; j++)
                    gload16(srcA[j] + k1, (char*)sA[cur ^ 1] + w * 2048 + j * 1024);
                gload16(srcBg + k1, (char*)sBg[cur ^ 1] + w * 1024);
                gload16(srcBu + k1, (char*)sBu[cur ^ 1] + w * 1024);
                FENCE; WAIT_VM(4); FENCE;
            } else {
                FENCE; WAIT_VM(0); FENCE;
            }
            bsync();
#pragma unroll
            for (int ks = 0; ks < 2; ++ks) {
                bf16x8 af[2], gf[4], uf[4];
#pragma unroll
                for (int mi = 0; mi < 2; mi++) af[mi] = *(const bf16x8*)((const char*)sA[cur] + aoff[mi][ks]);
#pragma unroll
                for (int nj = 0; nj < 4; nj++) {
                    gf[nj] = *(const bf16x8*)((const char*)sBg[cur] + boff[nj][ks]);
                    uf[nj] = *(const bf16x8*)((const char*)sBu[cur] + boff[nj][ks]);
                }
#pragma unroll
                for (int mi = 0; mi < 2; mi++)
#pragma unroll
                    for (int nj = 0; nj < 4; nj++) {
                        ag[mi][nj] = MFMA16(af[mi], gf[nj], ag[mi][nj]);
                        au[mi][nj] = MFMA16(af[mi], uf[nj], au[mi][nj]);
                    }
            }
        }

        bsync();
        char* sH = (char*)sA;
#pragma unroll
        for (int mi = 0; mi < 2; mi++)
#pragma unroll
            for (int jj = 0; jj < 4; jj++) {
                int r = wm * 32 + mi * 16 + fo * 4 + jj;
#pragma unroll
                for (int nj = 0; nj < 4; nj++) {
                    int c = wn * 64 + nj * 16 + fr;
                    float g = ag[mi][nj][jj];
                    float u = au[mi][nj][jj];
                    float h = (g / (1.f + __expf(-g))) * u;
                    *(unsigned short*)(sH + swz256((unsigned)(r * 256 + c * 2))) = f2bf(h);
                }
            }
        asm volatile("s_waitcnt lgkmcnt(0)" ::: "memory");
        bsync();
#pragma unroll
        for (int q = 0; q < 4; q++) {
            int idx = q * 1024 + t;
            int r = idx >> 4, c16 = idx & 15;
            if (r < rv) {
                uint4 v = *(const uint4*)(sH + swz256((unsigned)(r * 256 + c16 * 16)));
                *(uint4*)(outp + (size_t)(obase + m0 + r) * Ntot + n0 + c16 * 8) = v;
            }
        }
        bsync();
    }
}

// Down GEMM, pure-DMA. BM=256, BN=128, BK=64, 1024 thr / 16 waves (8m x 2n).
__global__ __launch_bounds__(1024, 4) void k_down10(
    const unsigned short* __restrict__ abuf, const unsigned short* __restrict__ hbuf,
    const unsigned short* __restrict__ wdb, const unsigned short* __restrict__ sdb,
    unsigned short* __restrict__ slots,
    const int* __restrict__ cnt, const int* __restrict__ offs,
    const int* __restrict__ etok, const float* __restrict__ ew) {
    __shared__ alignas(16) unsigned short sA[2][BM * BK];   // 2 x 32 KB
    __shared__ alignas(16) unsigned short sB[2][128 * BK];  // 2 x 16 KB

    const int bx = blockIdx.x, t = threadIdx.x;
    const int lane = t & 63, w = t >> 6;
    const int wm = w >> 1, wn = w & 1;
    const int fr = lane & 15, fo = lane >> 4;

    const bool routed = bx >= DWN_SH;
    int n0, m_start, m_stop, K, KT;
    const unsigned short* W;
    const unsigned short* Abuf;
    size_t arow0 = 0;
    const int* etk = nullptr; const float* ewe = nullptr;
    if (routed) {
        int rx = bx - DWN_SH;
        int e = rx / 16; n0 = (rx % 16) * 128;
        int M = cnt[e];
        if (M <= 0) return;
        m_start = 0; m_stop = M;
        K = INTER; KT = INTER / BK;
        W = wdb + (size_t)e * HID * INTER + (size_t)n0 * INTER;
        Abuf = abuf; arow0 = offs[e];
        etk = etok + e * TTOK; ewe = ew + e * TTOK;
    } else {
        n0 = (bx >> 2) * 128;
        m_start = (bx & 3) * 512; m_stop = m_start + 512;
        K = SINTER; KT = SINTER / BK;
        W = sdb + (size_t)n0 * SINTER;
        Abuf = hbuf;
    }

    const int browo = lane >> 3;
    const int achunk = (lane & 7) ^ browo;
    const unsigned short* srcB = W + (size_t)(w * 8 + browo) * K + achunk * 8;

    unsigned aoff[2][2], boff[4][2];
#pragma unroll
    for (int mi = 0; mi < 2; mi++)
#pragma unroll
        for (int ks = 0; ks < 2; ks++)
            aoff[mi][ks] = swz((unsigned)((wm * 32 + mi * 16 + fr) * 128 + ks * 64 + fo * 16));
#pragma unroll
    for (int nj = 0; nj < 4; nj++)
#pragma unroll
        for (int ks = 0; ks < 2; ks++)
            boff[nj][ks] = swz((unsigned)((wn * 64 + nj * 16 + fr) * 128 + ks * 64 + fo * 16));

    for (int m0 = m_start; m0 < m_stop; m0 += BM) {
        const int rv = min(m_stop - m0, BM);
        const unsigned short* srcA[2];
#pragma unroll
        for (int j = 0; j < 2; j++) {
            int r = w * 16 + j * 8 + browo;
            int rr = r < rv ? r : rv - 1;
            srcA[j] = Abuf + (arow0 + m0 + rr) * (size_t)K + achunk * 8;
        }

        f32x4 ac[2][4];
#pragma unroll
        for (int mi = 0; mi < 2; mi++)
#pragma unroll
            for (int nj = 0; nj < 4; nj++) ac[mi][nj] = {0.f, 0.f, 0.f, 0.f};

#pragma unroll
        for (int j = 0; j < 2; j++)
            gload16(srcA[j], (char*)sA[0] + w * 2048 + j * 1024);
        gload16(srcB, (char*)sB[0] + w * 1024);

        for (int kk = 0; kk < KT; ++kk) {
            const int cur = kk & 1;
            bsync();
            if (kk + 1 < KT) {
                const int k1 = (kk + 1) * BK;
#pragma unroll
                for (int j = 0; j < 2; j++)
                    gload16(srcA[j] + k1, (char*)sA[cur ^ 1] + w * 2048 + j * 1024);
                gload16(srcB + k1, (char*)sB[cur ^ 1] + w * 1024);
                FENCE; WAIT_VM(3); FENCE;
            } else {
                FENCE; WAIT_VM(0); FENCE;
            }
            bsync();
#pragma unroll
            for (int ks = 0; ks < 2; ++ks) {
                bf16x8 af[2], bf[4];
#pragma unroll
                for (int mi = 0; mi < 2; mi++) af[mi] = *(const bf16x8*)((const char*)sA[cur] + aoff[mi][ks]);
#pragma unroll
                for (int nj = 0; nj < 4; nj++) bf[nj] = *(const bf16x8*)((const char*)sB[cur] + boff[nj][ks]);
#pragma unroll
                for (int mi = 0; mi < 2; mi++)
#pragma unroll
                    for (int nj = 0; nj < 4; nj++)
                        ac[mi][nj] = MFMA16(af[mi], bf[nj], ac[mi][nj]);
            }
        }

        bsync();
        char* sH = (char*)sA;
#pragma unroll
        for (int mi = 0; mi < 2; mi++)
#pragma unroll
            for (int jj = 0; jj < 4; jj++) {
                int r = wm * 32 + mi * 16 + fo * 4 + jj;
                float wt = 1.f;
                if (routed) wt = (r < rv) ? ewe[m0 + r] : 0.f;
#pragma unroll
                for (int nj = 0; nj < 4; nj++) {
                    int c = wn * 64 + nj * 16 + fr;
                    *(unsigned short*)(sH + swz256((unsigned)(r * 256 + c * 2))) =
                        f2bf(ac[mi][nj][jj] * wt);
                }
            }
        asm volatile("s_waitcnt lgkmcnt(0)" ::: "memory");
        bsync();
#pragma unroll
        for (int q = 0; q < 4; q++) {
            int idx = q * 1024 + t;
            int r = idx >> 4, c16 = idx & 15;
            if (r < rv) {
                uint4 v = *(const uint4*)(sH + swz256((unsigned)(r * 256 + c16 * 16)));
                int tok, slice;
                if (routed) { int entry = etk[m0 + r]; tok = entry >> 1; slice = entry & 1; }
                else        { tok = m0 + r; slice = 2; }
                *(uint4*)(slots + ((size_t)slice * TTOK + tok) * HID + n0 + c16 * 8) = v;
            }
        }
        bsync();
    }
}

__global__ __launch_bounds__(256) void k_final(float* __restrict__ out,
                                               const unsigned short* __restrict__ slots) {
    size_t i = ((size_t)blockIdx.x * 256 + threadIdx.x) * 8;
    u16x8 s0 = *(const u16x8*)(slots + i);
    u16x8 s1 = *(const u16x8*)(slots + (size_t)TTOK * HID + i);
    u16x8 s2 = *(const u16x8*)(slots + (size_t)2 * TTOK * HID + i);
    float4 o0, o1;
    o0.x = bf2f(s0[0]) + bf2f(s1[0]) + bf2f(s2[0]);
    o0.y = bf2f(s0[1]) + bf2f(s1[1]) + bf2f(s2[1]);
    o0.z = bf2f(s0[2]) + bf2f(s1[2]) + bf2f(s2[2]);
    o0.w = bf2f(s0[3]) + bf2f(s1[3]) + bf2f(s2[3]);
    o1.x = bf2f(s0[4]) + bf2f(s1[4]) + bf2f(s2[4]);
    o1.y = bf2f(s0[5]) + bf2f(s1[5]) + bf2f(s2[5]);
    o1.z = bf2f(s0[6]) + bf2f(s1[6]) + bf2f(s2[6]);
    o1.w = bf2f(s0[7]) + bf2f(s1[7]) + bf2f(s2[7]);
    *(float4*)(out + i) = o0;
    *(float4*)(out + i + 4) = o1;
}

extern "C" void kernel_launch(void* const* d_in, const int* in_sizes, int n_in,
                              void* d_out, int out_size, void* d_ws, size_t ws_size,
                              hipStream_t stream) {
    const float* x = (const float*)d_in[0];
    const float* gate_w = (const float*)d_in[1];
    const float* cls_w = (const float*)d_in[2];
    const float* escale = (const float*)d_in[3];
    const float* ebias = (const float*)d_in[4];
    const float* wg = (const float*)d_in[5];
    const float* wu = (const float*)d_in[6];
    const float* wd = (const float*)d_in[7];
    const float* sg = (const float*)d_in[8];
    const float* su = (const float*)d_in[9];
    const float* sd = (const float*)d_in[10];
    float* out = (float*)d_out;

    char* ws = (char*)d_ws;
    size_t o = 0;
    auto alloc = [&](size_t bytes) {
        char* p = ws + o;
        o += (bytes + 255) & ~(size_t)255;
        return p;
    };
    const size_t WN = (size_t)NEXP * INTER * HID;
    const size_t SN = (size_t)SINTER * HID;
    unsigned short* xb    = (unsigned short*)alloc((size_t)TTOK * HID * 2);
    unsigned short* hbuf  = (unsigned short*)alloc((size_t)TTOK * SINTER * 2);
    unsigned short* abuf  = (unsigned short*)alloc((size_t)2 * TTOK * INTER * 2);
    unsigned short* slots = (unsigned short*)alloc((size_t)3 * TTOK * HID * 2);
    unsigned short* wgb   = (unsigned short*)alloc(WN * 2);
    unsigned short* wub   = (unsigned short*)alloc(WN * 2);
    unsigned short* wdb   = (unsigned short*)alloc(WN * 2);
    unsigned short* sgb   = (unsigned short*)alloc(SN * 2);
    unsigned short* subb  = (unsigned short*)alloc(SN * 2);
    unsigned short* sdb   = (unsigned short*)alloc(SN * 2);
    int* cnt              = (int*)alloc(256);
    int* offs             = (int*)alloc(256);
    int* etok             = (int*)alloc((size_t)NEXP * TTOK * 4);
    float* ew             = (float*)alloc((size_t)NEXP * TTOK * 4);

    k_zero<<<1, 64, 0, stream>>>(cnt);
    k_w2b<<<4096, 256, 0, stream>>>(wg, wgb, (int)(WN / 8));
    k_w2b<<<4096, 256, 0, stream>>>(wu, wub, (int)(WN / 8));
    k_w2b<<<4096, 256, 0, stream>>>(wd, wdb, (int)(WN / 8));
    k_w2b<<<1024, 256, 0, stream>>>(sg, sgb, (int)(SN / 8));
    k_w2b<<<1024, 256, 0, stream>>>(su, subb, (int)(SN / 8));
    k_w2b<<<1024, 256, 0, stream>>>(sd, sdb, (int)(SN / 8));
    k_w2b<<<2048, 256, 0, stream>>>(x, xb, (int)((size_t)TTOK * HID / 8));
    k_router<<<512, 256, 0, stream>>>(x, gate_w, cls_w, escale, ebias, cnt, etok, ew);
    k_offsets<<<1, 64, 0, stream>>>(cnt, offs);
    k_glu10<<<GLU_SH + GLU_RT, 1024, 0, stream>>>(
        xb, wgb, wub, sgb, subb, abuf, hbuf, cnt, offs, etok);
    k_down10<<<DWN_SH + DWN_RT, 1024, 0, stream>>>(
        abuf, hbuf, wdb, sdb, slots, cnt, offs, etok, ew);
    k_final<<<2048, 256, 0, stream>>>(out, slots);
}